// Round 1
// baseline (13296.127 us; speedup 1.0000x reference)
//
#include <hip/hip_runtime.h>

#define N_ 256
#define T_ 64
#define D_ 1024
#define H_ 1024
#define G_ 4096   // 4*H
#define P_ 16     // 4x4 spatial positions
#define INV_SQRT_H 0.03125f  // 1/sqrt(1024)

__device__ __forceinline__ float fsig(float x) {
    return 1.0f / (1.0f + __expf(-x));
}
__device__ __forceinline__ float ftanh(float x) {
    // tanh(x) = 1 - 2/(exp(2x)+1); saturates correctly at +-inf
    return 1.0f - 2.0f / (__expf(2.0f * x) + 1.0f);
}

// Block-wide reduction of 16 per-thread partials; block must be 256 threads.
// Result stored to dst[0..15] by threads 0..15.
__device__ __forceinline__ void block_reduce16_store(float* sc, float* __restrict__ dst, int tid) {
    #pragma unroll
    for (int off = 32; off > 0; off >>= 1) {
        #pragma unroll
        for (int p = 0; p < P_; ++p) sc[p] += __shfl_down(sc[p], off);
    }
    __shared__ float red[4][P_];
    int lane = tid & 63;
    int wv = tid >> 6;
    if (lane == 0) {
        #pragma unroll
        for (int p = 0; p < P_; ++p) red[wv][p] = sc[p];
    }
    __syncthreads();
    if (tid < P_) dst[tid] = red[0][tid] + red[1][tid] + red[2][tid] + red[3][tid];
}

// h0 = c0 = mean_p A[n,h,p]; scores0[n,p] = sum_h h0[n,h]*A[n,h,p]
// grid = N_, block = 256 (each thread handles 4 h values)
__global__ __launch_bounds__(256) void init_kernel(
    const float* __restrict__ A,
    float* __restrict__ h0,
    float* __restrict__ c0,
    float* __restrict__ scores0)
{
    const int n = blockIdx.x;
    const int tid = threadIdx.x;
    const float* An = A + (size_t)n * H_ * P_;

    float sc[P_];
    #pragma unroll
    for (int p = 0; p < P_; ++p) sc[p] = 0.0f;

    #pragma unroll
    for (int r = 0; r < 4; ++r) {
        int h = tid + 256 * r;
        const float4* row = (const float4*)(An + (size_t)h * P_);
        float ar[P_];
        float4* arv = (float4*)ar;
        arv[0] = row[0]; arv[1] = row[1]; arv[2] = row[2]; arv[3] = row[3];
        float s = 0.0f;
        #pragma unroll
        for (int p = 0; p < P_; ++p) s += ar[p];
        float hm = s * (1.0f / 16.0f);
        h0[(size_t)n * H_ + h] = hm;
        c0[(size_t)n * H_ + h] = hm;
        #pragma unroll
        for (int p = 0; p < P_; ++p) sc[p] += hm * ar[p];
    }
    block_reduce16_store(sc, scores0 + (size_t)n * P_, tid);
}

// w = softmax(scores_t[n,:] * inv_sqrt_h); attn[n,h] = sum_p A[n,h,p]*w[p]
// grid = N_, block = 256
__global__ __launch_bounds__(256) void attn_kernel(
    const float* __restrict__ A,
    const float* __restrict__ scores_t,
    float* __restrict__ attn)
{
    const int n = blockIdx.x;
    const int tid = threadIdx.x;
    __shared__ float w[P_];
    if (tid == 0) {
        float s[P_];
        float m = -1e30f;
        #pragma unroll
        for (int p = 0; p < P_; ++p) {
            s[p] = scores_t[(size_t)n * P_ + p] * INV_SQRT_H;
            m = fmaxf(m, s[p]);
        }
        float sum = 0.0f;
        #pragma unroll
        for (int p = 0; p < P_; ++p) { s[p] = __expf(s[p] - m); sum += s[p]; }
        float inv = 1.0f / sum;
        #pragma unroll
        for (int p = 0; p < P_; ++p) w[p] = s[p] * inv;
    }
    __syncthreads();
    float wl[P_];
    #pragma unroll
    for (int p = 0; p < P_; ++p) wl[p] = w[p];

    const float* An = A + (size_t)n * H_ * P_;
    #pragma unroll
    for (int r = 0; r < 4; ++r) {
        int h = tid + 256 * r;
        const float4* row = (const float4*)(An + (size_t)h * P_);
        float ar[P_];
        float4* arv = (float4*)ar;
        arv[0] = row[0]; arv[1] = row[1]; arv[2] = row[2]; arv[3] = row[3];
        float a = 0.0f;
        #pragma unroll
        for (int p = 0; p < P_; ++p) a = fmaf(ar[p], wl[p], a);
        attn[(size_t)n * H_ + h] = a;
    }
}

// a_buf[n,j] = x[n,t,:]@Wx[:,j] + h_prev[n,:]@Wh[:,j] + attn[n,:]@Wattn[:,j] + b[j]
// grid = (G_/64, N_/64) = (64,4) = 256 blocks, block = 256 threads
// Tile: 64(n) x 64(j), BK=32, microtile 4x4 per thread.
__global__ __launch_bounds__(256) void gemm_kernel(
    const float* __restrict__ x, int t,
    const float* __restrict__ h_prev,
    const float* __restrict__ attn,
    const float* __restrict__ Wx,
    const float* __restrict__ Wh,
    const float* __restrict__ Wattn,
    const float* __restrict__ b,
    float* __restrict__ a_buf)
{
    __shared__ float As[64][32];
    __shared__ float Bs[32][64];

    const int tid = threadIdx.x;
    const int j0 = blockIdx.x * 64;
    const int n0 = blockIdx.y * 64;
    const int tj = tid & 15;
    const int tn = tid >> 4;
    const int nn0 = tn * 4;
    const int jj0 = tj * 4;

    float acc[4][4];
    #pragma unroll
    for (int r = 0; r < 4; ++r)
        #pragma unroll
        for (int c = 0; c < 4; ++c) acc[r][c] = 0.0f;

    // K = 3072 (x-part 1024 | h-part 1024 | attn-part 1024), 96 tiles of 32
    for (int kt = 0; kt < 96; ++kt) {
        const int k0 = kt * 32;
        const int phase = k0 >> 10;       // 0: x/Wx, 1: h/Wh, 2: attn/Wattn
        const int klocal = k0 & 1023;

        __syncthreads();  // previous compute must finish before restaging

        // Stage A-tile: 64 x 32, 2 float4 per thread, contiguous in LDS
        #pragma unroll
        for (int i = 0; i < 2; ++i) {
            int f = tid + 256 * i;
            int nn = f >> 3;
            int kk4 = (f & 7) << 2;
            int n = n0 + nn;
            int k = klocal + kk4;
            const float4* src;
            if (phase == 0)      src = (const float4*)(x + ((size_t)n * T_ + t) * D_ + k);
            else if (phase == 1) src = (const float4*)(h_prev + (size_t)n * H_ + k);
            else                 src = (const float4*)(attn + (size_t)n * H_ + k);
            *(float4*)(&As[nn][kk4]) = *src;
        }
        // Stage B-tile: 32 x 64, 2 float4 per thread
        const float* Wsrc = (phase == 0) ? Wx : (phase == 1) ? Wh : Wattn;
        #pragma unroll
        for (int i = 0; i < 2; ++i) {
            int f = tid + 256 * i;
            int kk = f >> 4;
            int jj4 = (f & 15) << 2;
            *(float4*)(&Bs[kk][jj4]) =
                *(const float4*)(Wsrc + (size_t)(klocal + kk) * G_ + j0 + jj4);
        }
        __syncthreads();

        #pragma unroll
        for (int kk0 = 0; kk0 < 32; kk0 += 4) {
            float4 af4[4], bf4[4];
            #pragma unroll
            for (int r = 0; r < 4; ++r) af4[r] = *(const float4*)(&As[nn0 + r][kk0]);
            #pragma unroll
            for (int s = 0; s < 4; ++s) bf4[s] = *(const float4*)(&Bs[kk0 + s][jj0]);
            const float* af = (const float*)af4;  // af[r*4+s]
            const float* bf = (const float*)bf4;  // bf[s*4+c]
            #pragma unroll
            for (int r = 0; r < 4; ++r)
                #pragma unroll
                for (int s = 0; s < 4; ++s) {
                    float av = af[r * 4 + s];
                    #pragma unroll
                    for (int c = 0; c < 4; ++c)
                        acc[r][c] = fmaf(av, bf[s * 4 + c], acc[r][c]);
                }
        }
    }

    const float4 bb = *(const float4*)(b + j0 + jj0);
    #pragma unroll
    for (int r = 0; r < 4; ++r) {
        float4 o;
        o.x = acc[r][0] + bb.x;
        o.y = acc[r][1] + bb.y;
        o.z = acc[r][2] + bb.z;
        o.w = acc[r][3] + bb.w;
        *(float4*)(a_buf + (size_t)(n0 + nn0 + r) * G_ + j0 + jj0) = o;
    }
}

// gates + cell update + output write + scores for next step
// grid = N_, block = 256 (each thread handles 4 m values)
__global__ __launch_bounds__(256) void gates_kernel(
    const float* __restrict__ a_buf,
    const float* __restrict__ A,
    float* __restrict__ c_buf,
    float* __restrict__ h_next,
    float* __restrict__ d_out, int t,
    float* __restrict__ scores_next)
{
    const int n = blockIdx.x;
    const int tid = threadIdx.x;
    const float* an = a_buf + (size_t)n * G_;
    const float* An = A + (size_t)n * H_ * P_;

    float sc[P_];
    #pragma unroll
    for (int p = 0; p < P_; ++p) sc[p] = 0.0f;

    #pragma unroll
    for (int r = 0; r < 4; ++r) {
        int m = tid + 256 * r;
        float ai = an[m];
        float af = an[m + 1024];
        float ao = an[m + 2048];
        float ag = an[m + 3072];
        float c = c_buf[(size_t)n * H_ + m];
        float nc = fsig(af) * c + fsig(ai) * ftanh(ag);
        float nh = fsig(ao) * ftanh(nc);
        c_buf[(size_t)n * H_ + m] = nc;
        h_next[(size_t)n * H_ + m] = nh;
        d_out[((size_t)n * T_ + t) * H_ + m] = nh;

        const float4* row = (const float4*)(An + (size_t)m * P_);
        float ar[P_];
        float4* arv = (float4*)ar;
        arv[0] = row[0]; arv[1] = row[1]; arv[2] = row[2]; arv[3] = row[3];
        #pragma unroll
        for (int p = 0; p < P_; ++p) sc[p] += nh * ar[p];
    }
    block_reduce16_store(sc, scores_next + (size_t)n * P_, tid);
}

extern "C" void kernel_launch(void* const* d_in, const int* in_sizes, int n_in,
                              void* d_out, int out_size, void* d_ws, size_t ws_size,
                              hipStream_t stream) {
    const float* x     = (const float*)d_in[0];  // (N,T,D)
    const float* A     = (const float*)d_in[1];  // (N,H,16)
    const float* Wx    = (const float*)d_in[2];  // (D,4H)
    const float* Wh    = (const float*)d_in[3];  // (H,4H)
    const float* Wattn = (const float*)d_in[4];  // (H,4H)
    const float* b     = (const float*)d_in[5];  // (4H,)
    float* out = (float*)d_out;                  // (N,T,H)

    // workspace layout (floats): ~9.5 MB total
    float* ws = (float*)d_ws;
    float* h_buf0 = ws;                                   // N*H
    float* h_buf1 = h_buf0 + (size_t)N_ * H_;             // N*H
    float* c_buf  = h_buf1 + (size_t)N_ * H_;             // N*H
    float* attn   = c_buf  + (size_t)N_ * H_;             // N*H
    float* a_buf  = attn   + (size_t)N_ * H_;             // N*4H
    float* scores = a_buf  + (size_t)N_ * G_;             // (T+1)*N*16

    init_kernel<<<N_, 256, 0, stream>>>(A, h_buf0, c_buf, scores);

    for (int t = 0; t < T_; ++t) {
        float* h_prev = (t & 1) ? h_buf1 : h_buf0;
        float* h_next = (t & 1) ? h_buf0 : h_buf1;

        attn_kernel<<<N_, 256, 0, stream>>>(A, scores + (size_t)t * N_ * P_, attn);

        dim3 gg(G_ / 64, N_ / 64);
        gemm_kernel<<<gg, 256, 0, stream>>>(x, t, h_prev, attn, Wx, Wh, Wattn, b, a_buf);

        gates_kernel<<<N_, 256, 0, stream>>>(a_buf, A, c_buf, h_next, out, t,
                                             scores + (size_t)(t + 1) * N_ * P_);
    }
}

// Round 2
// 3091.162 us; speedup vs baseline: 4.3013x; 4.3013x over previous
//
#include <hip/hip_runtime.h>

#define N_ 256
#define T_ 64
#define D_ 1024
#define H_ 1024
#define G_ 4096   // 4*H
#define P_ 16     // 4x4 spatial positions
#define KTOT 3072 // D + H + H
#define INV_SQRT_H 0.03125f
#define KSPLIT 8
#define KPB 384   // K per split-K block (12 k-steps of 32)

typedef __attribute__((ext_vector_type(8))) short short8_t;
typedef __attribute__((ext_vector_type(4))) float f32x4;

__device__ __forceinline__ unsigned short f2bf(float f) {
    unsigned int u = __float_as_uint(f);
    unsigned int r = (u + 0x7FFFu + ((u >> 16) & 1u)) >> 16;  // RNE
    return (unsigned short)r;
}
__device__ __forceinline__ float bf2f(unsigned short h) {
    return __uint_as_float(((unsigned int)h) << 16);
}
__device__ __forceinline__ float fsig(float x) { return 1.0f / (1.0f + __expf(-x)); }
__device__ __forceinline__ float ftanh(float x) { return 1.0f - 2.0f / (__expf(2.0f * x) + 1.0f); }

// ---------------------------------------------------------------------------
// Transpose + hi/lo-split weights into WT_hi/WT_lo: (4096 j) x (3072 k) bf16,
// k-concat [Wx | Wh | Wattn]. grid (64, 16, 3), block 256.
// ---------------------------------------------------------------------------
__global__ __launch_bounds__(256) void prep_weights(
    const float* __restrict__ Wx, const float* __restrict__ Wh,
    const float* __restrict__ Wattn,
    unsigned short* __restrict__ WT_hi, unsigned short* __restrict__ WT_lo)
{
    __shared__ float tr[64][65];
    const int tid = threadIdx.x;
    const int j0 = blockIdx.x * 64;
    const int k0 = blockIdx.y * 64;
    const int mat = blockIdx.z;
    const float* src = (mat == 0) ? Wx : (mat == 1) ? Wh : Wattn;
    const int koff = mat * 1024;

    #pragma unroll
    for (int l = 0; l < 4; ++l) {
        const int flat = l * 256 + tid;
        const int kk = flat >> 4;
        const int jj4 = (flat & 15) * 4;
        float4 v = *(const float4*)(src + (size_t)(k0 + kk) * G_ + j0 + jj4);
        tr[kk][jj4] = v.x; tr[kk][jj4 + 1] = v.y; tr[kk][jj4 + 2] = v.z; tr[kk][jj4 + 3] = v.w;
    }
    __syncthreads();
    #pragma unroll
    for (int l = 0; l < 8; ++l) {
        const int flat = l * 256 + tid;
        const int jj = flat >> 5;
        const int kk = (flat & 31) * 2;
        float v0 = tr[kk][jj], v1 = tr[kk + 1][jj];
        size_t o = (size_t)(j0 + jj) * KTOT + koff + k0 + kk;
        ushort2 h, lo;
        h.x = f2bf(v0); h.y = f2bf(v1);
        lo.x = f2bf(v0 - bf2f(h.x)); lo.y = f2bf(v1 - bf2f(h.y));
        *(ushort2*)&WT_hi[o] = h;
        *(ushort2*)&WT_lo[o] = lo;
    }
}

// ---------------------------------------------------------------------------
// init: h0=c0=mean_p A; scores0 -> softmax -> attn0; write ha=[h0|attn0] hi/lo.
// grid N_, block 256; thread handles 4 consecutive h (m0=tid*4).
// ---------------------------------------------------------------------------
__global__ __launch_bounds__(256) void init_kernel(
    const float* __restrict__ A,
    float* __restrict__ c_buf,
    unsigned short* __restrict__ ha_hi, unsigned short* __restrict__ ha_lo)
{
    const int n = blockIdx.x, tid = threadIdx.x;
    const int m0 = tid * 4;
    const float* An = A + (size_t)n * H_ * P_;
    __shared__ float sred[4][P_];
    __shared__ float wsh[P_];

    float ar[4][P_];
    float hv[4];
    float sc[P_];
    #pragma unroll
    for (int p = 0; p < P_; ++p) sc[p] = 0.0f;

    #pragma unroll
    for (int r = 0; r < 4; ++r) {
        const float4* row = (const float4*)(An + (size_t)(m0 + r) * P_);
        float4 v0 = row[0], v1 = row[1], v2 = row[2], v3 = row[3];
        ar[r][0]=v0.x; ar[r][1]=v0.y; ar[r][2]=v0.z; ar[r][3]=v0.w;
        ar[r][4]=v1.x; ar[r][5]=v1.y; ar[r][6]=v1.z; ar[r][7]=v1.w;
        ar[r][8]=v2.x; ar[r][9]=v2.y; ar[r][10]=v2.z; ar[r][11]=v2.w;
        ar[r][12]=v3.x; ar[r][13]=v3.y; ar[r][14]=v3.z; ar[r][15]=v3.w;
        float s = 0.0f;
        #pragma unroll
        for (int p = 0; p < P_; ++p) s += ar[r][p];
        hv[r] = s * (1.0f / 16.0f);
        #pragma unroll
        for (int p = 0; p < P_; ++p) sc[p] += hv[r] * ar[r][p];
    }
    // write c0 and ha h-part
    float4 c4; c4.x = hv[0]; c4.y = hv[1]; c4.z = hv[2]; c4.w = hv[3];
    *(float4*)(c_buf + (size_t)n * H_ + m0) = c4;
    ushort4 hh, hl;
    hh.x=f2bf(hv[0]); hh.y=f2bf(hv[1]); hh.z=f2bf(hv[2]); hh.w=f2bf(hv[3]);
    hl.x=f2bf(hv[0]-bf2f(hh.x)); hl.y=f2bf(hv[1]-bf2f(hh.y));
    hl.z=f2bf(hv[2]-bf2f(hh.z)); hl.w=f2bf(hv[3]-bf2f(hh.w));
    *(ushort4*)&ha_hi[(size_t)n * 2048 + m0] = hh;
    *(ushort4*)&ha_lo[(size_t)n * 2048 + m0] = hl;

    // block-reduce scores
    #pragma unroll
    for (int off = 32; off > 0; off >>= 1)
        #pragma unroll
        for (int p = 0; p < P_; ++p) sc[p] += __shfl_down(sc[p], off);
    if ((tid & 63) == 0) {
        #pragma unroll
        for (int p = 0; p < P_; ++p) sred[tid >> 6][p] = sc[p];
    }
    __syncthreads();
    if (tid == 0) {
        float s[P_], m = -1e30f;
        #pragma unroll
        for (int p = 0; p < P_; ++p) {
            s[p] = (sred[0][p] + sred[1][p] + sred[2][p] + sred[3][p]) * INV_SQRT_H;
            m = fmaxf(m, s[p]);
        }
        float sum = 0.0f;
        #pragma unroll
        for (int p = 0; p < P_; ++p) { s[p] = __expf(s[p] - m); sum += s[p]; }
        float inv = 1.0f / sum;
        #pragma unroll
        for (int p = 0; p < P_; ++p) wsh[p] = s[p] * inv;
    }
    __syncthreads();
    float w[P_];
    #pragma unroll
    for (int p = 0; p < P_; ++p) w[p] = wsh[p];
    float at[4];
    #pragma unroll
    for (int r = 0; r < 4; ++r) {
        float a = 0.0f;
        #pragma unroll
        for (int p = 0; p < P_; ++p) a = fmaf(ar[r][p], w[p], a);
        at[r] = a;
    }
    ushort4 th, tl;
    th.x=f2bf(at[0]); th.y=f2bf(at[1]); th.z=f2bf(at[2]); th.w=f2bf(at[3]);
    tl.x=f2bf(at[0]-bf2f(th.x)); tl.y=f2bf(at[1]-bf2f(th.y));
    tl.z=f2bf(at[2]-bf2f(th.z)); tl.w=f2bf(at[3]-bf2f(th.w));
    *(ushort4*)&ha_hi[(size_t)n * 2048 + 1024 + m0] = th;
    *(ushort4*)&ha_lo[(size_t)n * 2048 + 1024 + m0] = tl;
}

// ---------------------------------------------------------------------------
// MFMA GEMM: parts[kz][n][j] = sum_{k in kz-range} Acat[n][k] * W[k][j]
// Acat = [x_t (f32, split on the fly) | ha (bf16 hi/lo)], B from WT (=W^T).
// BM=BN=128, BK=32, 4 waves (2x2), wave tile 64x64 (mt=nt=4), 3-pass hi/lo.
// grid (32, 2, KSPLIT), block 256.
// ---------------------------------------------------------------------------
__global__ __launch_bounds__(256) void gemm_kernel(
    const float* __restrict__ x, int t,
    const unsigned short* __restrict__ ha_hi, const unsigned short* __restrict__ ha_lo,
    const unsigned short* __restrict__ WT_hi, const unsigned short* __restrict__ WT_lo,
    float* __restrict__ parts)
{
    __shared__ unsigned short Ahi[128][40], Alo[128][40], Bhi[128][40], Blo[128][40];
    const int tid = threadIdx.x;
    const int j0 = blockIdx.x * 128;
    const int n0 = blockIdx.y * 128;
    const int kz = blockIdx.z;
    const int w = tid >> 6, lane = tid & 63;
    const int wm = w & 1, wn = w >> 1;
    const int quad = lane >> 4, l15 = lane & 15;

    f32x4 acc[4][4];
    #pragma unroll
    for (int mt = 0; mt < 4; ++mt)
        #pragma unroll
        for (int nt = 0; nt < 4; ++nt) acc[mt][nt] = (f32x4){0.f, 0.f, 0.f, 0.f};

    const int ia = tid >> 3;          // phase-0 A staging row base
    const int ka4 = (tid & 7) * 4;
    const int i2 = tid >> 1;          // row 0..127 for bf16/B staging
    const int half16 = (tid & 1) * 16;

    for (int ks = 0; ks < KPB / 32; ++ks) {
        const int kglob = kz * KPB + ks * 32;
        const int phase = kglob >> 10;
        __syncthreads();
        // ---- stage B (always bf16 from WT) ----
        {
            const size_t bb = (size_t)(j0 + i2) * KTOT + kglob + half16;
            float4 b0 = *(const float4*)(WT_hi + bb);
            float4 b1 = *(const float4*)(WT_hi + bb + 8);
            *(float4*)&Bhi[i2][half16] = b0;
            *(float4*)&Bhi[i2][half16 + 8] = b1;
            float4 c0 = *(const float4*)(WT_lo + bb);
            float4 c1 = *(const float4*)(WT_lo + bb + 8);
            *(float4*)&Blo[i2][half16] = c0;
            *(float4*)&Blo[i2][half16 + 8] = c1;
        }
        // ---- stage A ----
        if (phase == 0) {
            #pragma unroll
            for (int l = 0; l < 4; ++l) {
                const int i = ia + 32 * l;
                float4 v = *(const float4*)(x + ((size_t)(n0 + i) * T_ + t) * D_ + kglob + ka4);
                ushort4 hi, lo;
                hi.x = f2bf(v.x); lo.x = f2bf(v.x - bf2f(hi.x));
                hi.y = f2bf(v.y); lo.y = f2bf(v.y - bf2f(hi.y));
                hi.z = f2bf(v.z); lo.z = f2bf(v.z - bf2f(hi.z));
                hi.w = f2bf(v.w); lo.w = f2bf(v.w - bf2f(hi.w));
                *(ushort4*)&Ahi[i][ka4] = hi;
                *(ushort4*)&Alo[i][ka4] = lo;
            }
        } else {
            const size_t ab = (size_t)(n0 + i2) * 2048 + (kglob - 1024) + half16;
            float4 a0 = *(const float4*)(ha_hi + ab);
            float4 a1 = *(const float4*)(ha_hi + ab + 8);
            *(float4*)&Ahi[i2][half16] = a0;
            *(float4*)&Ahi[i2][half16 + 8] = a1;
            a0 = *(const float4*)(ha_lo + ab);
            a1 = *(const float4*)(ha_lo + ab + 8);
            *(float4*)&Alo[i2][half16] = a0;
            *(float4*)&Alo[i2][half16 + 8] = a1;
        }
        __syncthreads();

        // ---- MFMA: 48 per wave per k-step ----
        short8_t bh[4], bl[4];
        #pragma unroll
        for (int nt = 0; nt < 4; ++nt) {
            const int jr = wn * 64 + nt * 16 + l15;
            bh[nt] = *(const short8_t*)&Bhi[jr][quad * 8];
            bl[nt] = *(const short8_t*)&Blo[jr][quad * 8];
        }
        #pragma unroll
        for (int mt = 0; mt < 4; ++mt) {
            const int mr = wm * 64 + mt * 16 + l15;
            short8_t ah = *(const short8_t*)&Ahi[mr][quad * 8];
            short8_t al = *(const short8_t*)&Alo[mr][quad * 8];
            #pragma unroll
            for (int nt = 0; nt < 4; ++nt) {
                acc[mt][nt] = __builtin_amdgcn_mfma_f32_16x16x32_bf16(al, bh[nt], acc[mt][nt], 0, 0, 0);
                acc[mt][nt] = __builtin_amdgcn_mfma_f32_16x16x32_bf16(ah, bl[nt], acc[mt][nt], 0, 0, 0);
                acc[mt][nt] = __builtin_amdgcn_mfma_f32_16x16x32_bf16(ah, bh[nt], acc[mt][nt], 0, 0, 0);
            }
        }
    }

    // epilogue: C/D layout col=lane&15, row=quad*4+reg (verified m89/m91)
    #pragma unroll
    for (int mt = 0; mt < 4; ++mt) {
        const int r0 = n0 + wm * 64 + mt * 16 + quad * 4;
        #pragma unroll
        for (int nt = 0; nt < 4; ++nt) {
            const int cc = j0 + wn * 64 + nt * 16 + l15;
            #pragma unroll
            for (int reg = 0; reg < 4; ++reg)
                parts[((size_t)kz * N_ + r0 + reg) * G_ + cc] = acc[mt][nt][reg];
        }
    }
}

// ---------------------------------------------------------------------------
// gates: a = sum_z parts + b; LSTM update; write d_out, ha h-part;
// then scores_{t+1} reduce + softmax + attn_{t+1} (fused, reuses A registers).
// grid N_, block 256; thread handles 4 consecutive h.
// ---------------------------------------------------------------------------
__global__ __launch_bounds__(256) void gates_kernel(
    const float* __restrict__ parts, const float* __restrict__ bvec,
    const float* __restrict__ A, float* __restrict__ c_buf,
    unsigned short* __restrict__ ha_hi, unsigned short* __restrict__ ha_lo,
    float* __restrict__ out, int t)
{
    const int n = blockIdx.x, tid = threadIdx.x;
    const int m0 = tid * 4;
    const float* An = A + (size_t)n * H_ * P_;
    __shared__ float sred[4][P_];
    __shared__ float wsh[P_];

    float ar[4][P_];
    #pragma unroll
    for (int r = 0; r < 4; ++r) {
        const float4* row = (const float4*)(An + (size_t)(m0 + r) * P_);
        float4 v0 = row[0], v1 = row[1], v2 = row[2], v3 = row[3];
        ar[r][0]=v0.x; ar[r][1]=v0.y; ar[r][2]=v0.z; ar[r][3]=v0.w;
        ar[r][4]=v1.x; ar[r][5]=v1.y; ar[r][6]=v1.z; ar[r][7]=v1.w;
        ar[r][8]=v2.x; ar[r][9]=v2.y; ar[r][10]=v2.z; ar[r][11]=v2.w;
        ar[r][12]=v3.x; ar[r][13]=v3.y; ar[r][14]=v3.z; ar[r][15]=v3.w;
    }

    float ga[4][4];  // [gate][r]
    #pragma unroll
    for (int g = 0; g < 4; ++g) {
        const int j = g * 1024 + m0;
        float4 s = *(const float4*)(bvec + j);
        #pragma unroll
        for (int z = 0; z < KSPLIT; ++z) {
            float4 p = *(const float4*)(parts + ((size_t)z * N_ + n) * G_ + j);
            s.x += p.x; s.y += p.y; s.z += p.z; s.w += p.w;
        }
        ga[g][0] = s.x; ga[g][1] = s.y; ga[g][2] = s.z; ga[g][3] = s.w;
    }

    float4 c4 = *(const float4*)(c_buf + (size_t)n * H_ + m0);
    float cold[4] = {c4.x, c4.y, c4.z, c4.w};
    float nh[4], ncv[4];
    #pragma unroll
    for (int r = 0; r < 4; ++r) {
        float nc = fsig(ga[1][r]) * cold[r] + fsig(ga[0][r]) * ftanh(ga[3][r]);
        ncv[r] = nc;
        nh[r] = fsig(ga[2][r]) * ftanh(nc);
    }
    float4 co; co.x = ncv[0]; co.y = ncv[1]; co.z = ncv[2]; co.w = ncv[3];
    *(float4*)(c_buf + (size_t)n * H_ + m0) = co;
    float4 ho; ho.x = nh[0]; ho.y = nh[1]; ho.z = nh[2]; ho.w = nh[3];
    *(float4*)(out + ((size_t)n * T_ + t) * H_ + m0) = ho;
    ushort4 hh, hl;
    hh.x=f2bf(nh[0]); hh.y=f2bf(nh[1]); hh.z=f2bf(nh[2]); hh.w=f2bf(nh[3]);
    hl.x=f2bf(nh[0]-bf2f(hh.x)); hl.y=f2bf(nh[1]-bf2f(hh.y));
    hl.z=f2bf(nh[2]-bf2f(hh.z)); hl.w=f2bf(nh[3]-bf2f(hh.w));
    *(ushort4*)&ha_hi[(size_t)n * 2048 + m0] = hh;
    *(ushort4*)&ha_lo[(size_t)n * 2048 + m0] = hl;

    // scores for t+1
    float sc[P_];
    #pragma unroll
    for (int p = 0; p < P_; ++p) {
        float s = 0.0f;
        #pragma unroll
        for (int r = 0; r < 4; ++r) s = fmaf(nh[r], ar[r][p], s);
        sc[p] = s;
    }
    #pragma unroll
    for (int off = 32; off > 0; off >>= 1)
        #pragma unroll
        for (int p = 0; p < P_; ++p) sc[p] += __shfl_down(sc[p], off);
    if ((tid & 63) == 0) {
        #pragma unroll
        for (int p = 0; p < P_; ++p) sred[tid >> 6][p] = sc[p];
    }
    __syncthreads();
    if (tid == 0) {
        float s[P_], m = -1e30f;
        #pragma unroll
        for (int p = 0; p < P_; ++p) {
            s[p] = (sred[0][p] + sred[1][p] + sred[2][p] + sred[3][p]) * INV_SQRT_H;
            m = fmaxf(m, s[p]);
        }
        float sum = 0.0f;
        #pragma unroll
        for (int p = 0; p < P_; ++p) { s[p] = __expf(s[p] - m); sum += s[p]; }
        float inv = 1.0f / sum;
        #pragma unroll
        for (int p = 0; p < P_; ++p) wsh[p] = s[p] * inv;
    }
    __syncthreads();
    float w[P_];
    #pragma unroll
    for (int p = 0; p < P_; ++p) w[p] = wsh[p];
    #pragma unroll
    for (int r = 0; r < 4; ++r) {
        float a = 0.0f;
        #pragma unroll
        for (int p = 0; p < P_; ++p) a = fmaf(ar[r][p], w[p], a);
        unsigned short th = f2bf(a);
        unsigned short tl = f2bf(a - bf2f(th));
        ha_hi[(size_t)n * 2048 + 1024 + m0 + r] = th;
        ha_lo[(size_t)n * 2048 + 1024 + m0 + r] = tl;
    }
}

extern "C" void kernel_launch(void* const* d_in, const int* in_sizes, int n_in,
                              void* d_out, int out_size, void* d_ws, size_t ws_size,
                              hipStream_t stream) {
    const float* x     = (const float*)d_in[0];
    const float* A     = (const float*)d_in[1];
    const float* Wx    = (const float*)d_in[2];
    const float* Wh    = (const float*)d_in[3];
    const float* Wattn = (const float*)d_in[4];
    const float* b     = (const float*)d_in[5];
    float* out = (float*)d_out;

    // workspace layout (~87 MB)
    unsigned short* WT_hi = (unsigned short*)d_ws;                 // 4096*3072
    unsigned short* WT_lo = WT_hi + (size_t)G_ * KTOT;             // 4096*3072
    unsigned short* ha_hi = WT_lo + (size_t)G_ * KTOT;             // 256*2048
    unsigned short* ha_lo = ha_hi + (size_t)N_ * 2048;             // 256*2048
    float* c_buf = (float*)(ha_lo + (size_t)N_ * 2048);            // 256*1024
    float* parts = c_buf + (size_t)N_ * H_;                        // 8*256*4096

    prep_weights<<<dim3(64, 16, 3), 256, 0, stream>>>(Wx, Wh, Wattn, WT_hi, WT_lo);
    init_kernel<<<N_, 256, 0, stream>>>(A, c_buf, ha_hi, ha_lo);

    for (int t = 0; t < T_; ++t) {
        gemm_kernel<<<dim3(32, 2, KSPLIT), 256, 0, stream>>>(
            x, t, ha_hi, ha_lo, WT_hi, WT_lo, parts);
        gates_kernel<<<N_, 256, 0, stream>>>(parts, b, A, c_buf, ha_hi, ha_lo, out, t);
    }
}

// Round 3
// 2530.378 us; speedup vs baseline: 5.2546x; 1.2216x over previous
//
#include <hip/hip_runtime.h>

#define N_ 256
#define T_ 64
#define D_ 1024
#define H_ 1024
#define G_ 4096   // 4*H
#define P_ 16     // 4x4 spatial positions
#define KTOT 3072 // D + H + H
#define INV_SQRT_H 0.03125f
#define KSPLIT 8
#define KPB 384   // K per split-K block (12 k-steps of 32)

typedef __attribute__((ext_vector_type(8))) short short8_t;
typedef __attribute__((ext_vector_type(4))) float f32x4;

__device__ __forceinline__ unsigned short f2bf(float f) {
    unsigned int u = __float_as_uint(f);
    unsigned int r = (u + 0x7FFFu + ((u >> 16) & 1u)) >> 16;  // RNE
    return (unsigned short)r;
}
__device__ __forceinline__ float bf2f(unsigned short h) {
    return __uint_as_float(((unsigned int)h) << 16);
}
__device__ __forceinline__ float fsig(float x) { return 1.0f / (1.0f + __expf(-x)); }
__device__ __forceinline__ float ftanh(float x) { return 1.0f - 2.0f / (__expf(2.0f * x) + 1.0f); }

// async global->LDS, 16 bytes per lane; LDS dest = uniform base + lane*16
__device__ __forceinline__ void gl_lds16(const void* g, void* l) {
    __builtin_amdgcn_global_load_lds(
        (const __attribute__((address_space(1))) unsigned int*)g,
        (__attribute__((address_space(3))) unsigned int*)l, 16, 0, 0);
}

// ---------------------------------------------------------------------------
// Transpose + hi/lo-split weights into WT_hi/WT_lo: (4096 j) x (3072 k) bf16,
// k-concat [Wx | Wh | Wattn]. grid (64, 16, 3), block 256.
// ---------------------------------------------------------------------------
__global__ __launch_bounds__(256) void prep_weights(
    const float* __restrict__ Wx, const float* __restrict__ Wh,
    const float* __restrict__ Wattn,
    unsigned short* __restrict__ WT_hi, unsigned short* __restrict__ WT_lo)
{
    __shared__ float tr[64][65];
    const int tid = threadIdx.x;
    const int j0 = blockIdx.x * 64;
    const int k0 = blockIdx.y * 64;
    const int mat = blockIdx.z;
    const float* src = (mat == 0) ? Wx : (mat == 1) ? Wh : Wattn;
    const int koff = mat * 1024;

    #pragma unroll
    for (int l = 0; l < 4; ++l) {
        const int flat = l * 256 + tid;
        const int kk = flat >> 4;
        const int jj4 = (flat & 15) * 4;
        float4 v = *(const float4*)(src + (size_t)(k0 + kk) * G_ + j0 + jj4);
        tr[kk][jj4] = v.x; tr[kk][jj4 + 1] = v.y; tr[kk][jj4 + 2] = v.z; tr[kk][jj4 + 3] = v.w;
    }
    __syncthreads();
    #pragma unroll
    for (int l = 0; l < 8; ++l) {
        const int flat = l * 256 + tid;
        const int jj = flat >> 5;
        const int kk = (flat & 31) * 2;
        float v0 = tr[kk][jj], v1 = tr[kk + 1][jj];
        size_t o = (size_t)(j0 + jj) * KTOT + koff + k0 + kk;
        ushort2 h, lo;
        h.x = f2bf(v0); h.y = f2bf(v1);
        lo.x = f2bf(v0 - bf2f(h.x)); lo.y = f2bf(v1 - bf2f(h.y));
        *(ushort2*)&WT_hi[o] = h;
        *(ushort2*)&WT_lo[o] = lo;
    }
}

// ---------------------------------------------------------------------------
// Split x into bf16 hi/lo (same layout as x: (N,T,D)). grid (N_,T_), block 256.
// ---------------------------------------------------------------------------
__global__ __launch_bounds__(256) void prep_x(
    const float* __restrict__ x,
    unsigned short* __restrict__ Xhi, unsigned short* __restrict__ Xlo)
{
    const int n = blockIdx.x, t = blockIdx.y, tid = threadIdx.x;
    const size_t o = ((size_t)n * T_ + t) * D_ + tid * 4;
    float4 v = *(const float4*)(x + o);
    ushort4 hi, lo;
    hi.x = f2bf(v.x); lo.x = f2bf(v.x - bf2f(hi.x));
    hi.y = f2bf(v.y); lo.y = f2bf(v.y - bf2f(hi.y));
    hi.z = f2bf(v.z); lo.z = f2bf(v.z - bf2f(hi.z));
    hi.w = f2bf(v.w); lo.w = f2bf(v.w - bf2f(hi.w));
    *(ushort4*)&Xhi[o] = hi;
    *(ushort4*)&Xlo[o] = lo;
}

// ---------------------------------------------------------------------------
// init: h0=c0=mean_p A; scores0 -> softmax -> attn0; write ha=[h0|attn0] hi/lo.
// grid N_, block 256; thread handles 4 consecutive h (m0=tid*4).
// ---------------------------------------------------------------------------
__global__ __launch_bounds__(256) void init_kernel(
    const float* __restrict__ A,
    float* __restrict__ c_buf,
    unsigned short* __restrict__ ha_hi, unsigned short* __restrict__ ha_lo)
{
    const int n = blockIdx.x, tid = threadIdx.x;
    const int m0 = tid * 4;
    const float* An = A + (size_t)n * H_ * P_;
    __shared__ float sred[4][P_];
    __shared__ float wsh[P_];

    float ar[4][P_];
    float hv[4];
    float sc[P_];
    #pragma unroll
    for (int p = 0; p < P_; ++p) sc[p] = 0.0f;

    #pragma unroll
    for (int r = 0; r < 4; ++r) {
        const float4* row = (const float4*)(An + (size_t)(m0 + r) * P_);
        float4 v0 = row[0], v1 = row[1], v2 = row[2], v3 = row[3];
        ar[r][0]=v0.x; ar[r][1]=v0.y; ar[r][2]=v0.z; ar[r][3]=v0.w;
        ar[r][4]=v1.x; ar[r][5]=v1.y; ar[r][6]=v1.z; ar[r][7]=v1.w;
        ar[r][8]=v2.x; ar[r][9]=v2.y; ar[r][10]=v2.z; ar[r][11]=v2.w;
        ar[r][12]=v3.x; ar[r][13]=v3.y; ar[r][14]=v3.z; ar[r][15]=v3.w;
        float s = 0.0f;
        #pragma unroll
        for (int p = 0; p < P_; ++p) s += ar[r][p];
        hv[r] = s * (1.0f / 16.0f);
        #pragma unroll
        for (int p = 0; p < P_; ++p) sc[p] += hv[r] * ar[r][p];
    }
    float4 c4; c4.x = hv[0]; c4.y = hv[1]; c4.z = hv[2]; c4.w = hv[3];
    *(float4*)(c_buf + (size_t)n * H_ + m0) = c4;
    ushort4 hh, hl;
    hh.x=f2bf(hv[0]); hh.y=f2bf(hv[1]); hh.z=f2bf(hv[2]); hh.w=f2bf(hv[3]);
    hl.x=f2bf(hv[0]-bf2f(hh.x)); hl.y=f2bf(hv[1]-bf2f(hh.y));
    hl.z=f2bf(hv[2]-bf2f(hh.z)); hl.w=f2bf(hv[3]-bf2f(hh.w));
    *(ushort4*)&ha_hi[(size_t)n * 2048 + m0] = hh;
    *(ushort4*)&ha_lo[(size_t)n * 2048 + m0] = hl;

    #pragma unroll
    for (int off = 32; off > 0; off >>= 1)
        #pragma unroll
        for (int p = 0; p < P_; ++p) sc[p] += __shfl_down(sc[p], off);
    if ((tid & 63) == 0) {
        #pragma unroll
        for (int p = 0; p < P_; ++p) sred[tid >> 6][p] = sc[p];
    }
    __syncthreads();
    if (tid == 0) {
        float s[P_], m = -1e30f;
        #pragma unroll
        for (int p = 0; p < P_; ++p) {
            s[p] = (sred[0][p] + sred[1][p] + sred[2][p] + sred[3][p]) * INV_SQRT_H;
            m = fmaxf(m, s[p]);
        }
        float sum = 0.0f;
        #pragma unroll
        for (int p = 0; p < P_; ++p) { s[p] = __expf(s[p] - m); sum += s[p]; }
        float inv = 1.0f / sum;
        #pragma unroll
        for (int p = 0; p < P_; ++p) wsh[p] = s[p] * inv;
    }
    __syncthreads();
    float w[P_];
    #pragma unroll
    for (int p = 0; p < P_; ++p) w[p] = wsh[p];
    float at[4];
    #pragma unroll
    for (int r = 0; r < 4; ++r) {
        float a = 0.0f;
        #pragma unroll
        for (int p = 0; p < P_; ++p) a = fmaf(ar[r][p], w[p], a);
        at[r] = a;
    }
    ushort4 th, tl;
    th.x=f2bf(at[0]); th.y=f2bf(at[1]); th.z=f2bf(at[2]); th.w=f2bf(at[3]);
    tl.x=f2bf(at[0]-bf2f(th.x)); tl.y=f2bf(at[1]-bf2f(th.y));
    tl.z=f2bf(at[2]-bf2f(th.z)); tl.w=f2bf(at[3]-bf2f(th.w));
    *(ushort4*)&ha_hi[(size_t)n * 2048 + 1024 + m0] = th;
    *(ushort4*)&ha_lo[(size_t)n * 2048 + 1024 + m0] = tl;
}

// ---------------------------------------------------------------------------
// MFMA GEMM with async global_load_lds staging.
// parts[kz][n][j] = sum_{k in kz} Acat[n][k] * W[k][j]
// Acat = [Xsplit(t) | ha], all bf16 hi/lo. BM=BN=128, BK=32, 4 waves (2x2),
// wave tile 64x64, 3-pass hi/lo. grid (32, 2, KSPLIT), block 256.
// LDS rows are unpadded 32 shorts (64 B); 16B-chunks XOR-swizzled by row&3:
// LDS[row][c] holds global chunk c^(row&3)  => fragment reads are 2-way
// bank-aliased only (free), and global_load_lds lane order matches.
// ---------------------------------------------------------------------------
__global__ __launch_bounds__(256) void gemm_kernel(
    const unsigned short* __restrict__ Xhi, const unsigned short* __restrict__ Xlo, int t,
    const unsigned short* __restrict__ ha_hi, const unsigned short* __restrict__ ha_lo,
    const unsigned short* __restrict__ WT_hi, const unsigned short* __restrict__ WT_lo,
    float* __restrict__ parts)
{
    __shared__ unsigned short Ahi[128][32], Alo[128][32], Bhi[128][32], Blo[128][32];
    const int tid = threadIdx.x;
    const int j0 = blockIdx.x * 128;
    const int n0 = blockIdx.y * 128;
    const int kz = blockIdx.z;
    const int w = tid >> 6, lane = tid & 63;
    const int wm = w & 1, wn = w >> 1;
    const int quad = lane >> 4, l15 = lane & 15;
    const int lrow = lane >> 2;                 // 0..15 within a 16-row slab
    const int gchunk = (lane & 3) ^ (lrow & 3); // swizzled global 16B chunk

    f32x4 acc[4][4];
    #pragma unroll
    for (int mt = 0; mt < 4; ++mt)
        #pragma unroll
        for (int nt = 0; nt < 4; ++nt) acc[mt][nt] = (f32x4){0.f, 0.f, 0.f, 0.f};

    for (int ks = 0; ks < KPB / 32; ++ks) {
        const int kglob = kz * KPB + ks * 32;
        const int phase0 = (kglob < 1024);
        // A source: x-split slab for k<1024, ha for k>=1024
        const unsigned short* pAhi;
        const unsigned short* pAlo;
        size_t rstride, coff;
        if (phase0) {
            pAhi = Xhi + (size_t)t * D_;  pAlo = Xlo + (size_t)t * D_;
            rstride = (size_t)T_ * D_;    coff = kglob;
        } else {
            pAhi = ha_hi;  pAlo = ha_lo;
            rstride = 2048;               coff = kglob - 1024;
        }

        __syncthreads();  // prior compute done before overwrite
        #pragma unroll
        for (int i = 0; i < 2; ++i) {
            const int row = w * 32 + i * 16 + lrow;   // per-lane row in tile
            const int rb = w * 32 + i * 16;           // uniform LDS slab base
            gl_lds16(pAhi + (size_t)(n0 + row) * rstride + coff + gchunk * 8, &Ahi[rb][0]);
            gl_lds16(pAlo + (size_t)(n0 + row) * rstride + coff + gchunk * 8, &Alo[rb][0]);
            gl_lds16(WT_hi + (size_t)(j0 + row) * KTOT + kglob + gchunk * 8, &Bhi[rb][0]);
            gl_lds16(WT_lo + (size_t)(j0 + row) * KTOT + kglob + gchunk * 8, &Blo[rb][0]);
        }
        __syncthreads();  // drains vmcnt (global_load_lds) + lgkm

        short8_t bh[4], bl[4];
        #pragma unroll
        for (int nt = 0; nt < 4; ++nt) {
            const int jr = wn * 64 + nt * 16 + l15;
            const int c = (quad ^ (jr & 3)) * 8;
            bh[nt] = *(const short8_t*)&Bhi[jr][c];
            bl[nt] = *(const short8_t*)&Blo[jr][c];
        }
        #pragma unroll
        for (int mt = 0; mt < 4; ++mt) {
            const int mr = wm * 64 + mt * 16 + l15;
            const int c = (quad ^ (mr & 3)) * 8;
            short8_t ah = *(const short8_t*)&Ahi[mr][c];
            short8_t al = *(const short8_t*)&Alo[mr][c];
            #pragma unroll
            for (int nt = 0; nt < 4; ++nt) {
                acc[mt][nt] = __builtin_amdgcn_mfma_f32_16x16x32_bf16(al, bh[nt], acc[mt][nt], 0, 0, 0);
                acc[mt][nt] = __builtin_amdgcn_mfma_f32_16x16x32_bf16(ah, bl[nt], acc[mt][nt], 0, 0, 0);
                acc[mt][nt] = __builtin_amdgcn_mfma_f32_16x16x32_bf16(ah, bh[nt], acc[mt][nt], 0, 0, 0);
            }
        }
    }

    // epilogue: C/D layout col=lane&15, row=quad*4+reg (verified m89/m91)
    #pragma unroll
    for (int mt = 0; mt < 4; ++mt) {
        const int r0 = n0 + wm * 64 + mt * 16 + quad * 4;
        #pragma unroll
        for (int nt = 0; nt < 4; ++nt) {
            const int cc = j0 + wn * 64 + nt * 16 + l15;
            #pragma unroll
            for (int reg = 0; reg < 4; ++reg)
                parts[((size_t)kz * N_ + r0 + reg) * G_ + cc] = acc[mt][nt][reg];
        }
    }
}

// ---------------------------------------------------------------------------
// gates: a = sum_z parts + b; LSTM update; write d_out, ha h-part;
// then scores_{t+1} reduce + softmax + attn_{t+1} (fused).
// grid N_, block 256; thread handles 4 consecutive h.
// ---------------------------------------------------------------------------
__global__ __launch_bounds__(256) void gates_kernel(
    const float* __restrict__ parts, const float* __restrict__ bvec,
    const float* __restrict__ A, float* __restrict__ c_buf,
    unsigned short* __restrict__ ha_hi, unsigned short* __restrict__ ha_lo,
    float* __restrict__ out, int t)
{
    const int n = blockIdx.x, tid = threadIdx.x;
    const int m0 = tid * 4;
    const float* An = A + (size_t)n * H_ * P_;
    __shared__ float sred[4][P_];
    __shared__ float wsh[P_];

    float ar[4][P_];
    #pragma unroll
    for (int r = 0; r < 4; ++r) {
        const float4* row = (const float4*)(An + (size_t)(m0 + r) * P_);
        float4 v0 = row[0], v1 = row[1], v2 = row[2], v3 = row[3];
        ar[r][0]=v0.x; ar[r][1]=v0.y; ar[r][2]=v0.z; ar[r][3]=v0.w;
        ar[r][4]=v1.x; ar[r][5]=v1.y; ar[r][6]=v1.z; ar[r][7]=v1.w;
        ar[r][8]=v2.x; ar[r][9]=v2.y; ar[r][10]=v2.z; ar[r][11]=v2.w;
        ar[r][12]=v3.x; ar[r][13]=v3.y; ar[r][14]=v3.z; ar[r][15]=v3.w;
    }

    float ga[4][4];
    #pragma unroll
    for (int g = 0; g < 4; ++g) {
        const int j = g * 1024 + m0;
        float4 s = *(const float4*)(bvec + j);
        #pragma unroll
        for (int z = 0; z < KSPLIT; ++z) {
            float4 p = *(const float4*)(parts + ((size_t)z * N_ + n) * G_ + j);
            s.x += p.x; s.y += p.y; s.z += p.z; s.w += p.w;
        }
        ga[g][0] = s.x; ga[g][1] = s.y; ga[g][2] = s.z; ga[g][3] = s.w;
    }

    float4 c4 = *(const float4*)(c_buf + (size_t)n * H_ + m0);
    float cold[4] = {c4.x, c4.y, c4.z, c4.w};
    float nh[4], ncv[4];
    #pragma unroll
    for (int r = 0; r < 4; ++r) {
        float nc = fsig(ga[1][r]) * cold[r] + fsig(ga[0][r]) * ftanh(ga[3][r]);
        ncv[r] = nc;
        nh[r] = fsig(ga[2][r]) * ftanh(nc);
    }
    float4 co; co.x = ncv[0]; co.y = ncv[1]; co.z = ncv[2]; co.w = ncv[3];
    *(float4*)(c_buf + (size_t)n * H_ + m0) = co;
    float4 ho; ho.x = nh[0]; ho.y = nh[1]; ho.z = nh[2]; ho.w = nh[3];
    *(float4*)(out + ((size_t)n * T_ + t) * H_ + m0) = ho;
    ushort4 hh, hl;
    hh.x=f2bf(nh[0]); hh.y=f2bf(nh[1]); hh.z=f2bf(nh[2]); hh.w=f2bf(nh[3]);
    hl.x=f2bf(nh[0]-bf2f(hh.x)); hl.y=f2bf(nh[1]-bf2f(hh.y));
    hl.z=f2bf(nh[2]-bf2f(hh.z)); hl.w=f2bf(nh[3]-bf2f(hh.w));
    *(ushort4*)&ha_hi[(size_t)n * 2048 + m0] = hh;
    *(ushort4*)&ha_lo[(size_t)n * 2048 + m0] = hl;

    float sc[P_];
    #pragma unroll
    for (int p = 0; p < P_; ++p) {
        float s = 0.0f;
        #pragma unroll
        for (int r = 0; r < 4; ++r) s = fmaf(nh[r], ar[r][p], s);
        sc[p] = s;
    }
    #pragma unroll
    for (int off = 32; off > 0; off >>= 1)
        #pragma unroll
        for (int p = 0; p < P_; ++p) sc[p] += __shfl_down(sc[p], off);
    if ((tid & 63) == 0) {
        #pragma unroll
        for (int p = 0; p < P_; ++p) sred[tid >> 6][p] = sc[p];
    }
    __syncthreads();
    if (tid == 0) {
        float s[P_], m = -1e30f;
        #pragma unroll
        for (int p = 0; p < P_; ++p) {
            s[p] = (sred[0][p] + sred[1][p] + sred[2][p] + sred[3][p]) * INV_SQRT_H;
            m = fmaxf(m, s[p]);
        }
        float sum = 0.0f;
        #pragma unroll
        for (int p = 0; p < P_; ++p) { s[p] = __expf(s[p] - m); sum += s[p]; }
        float inv = 1.0f / sum;
        #pragma unroll
        for (int p = 0; p < P_; ++p) wsh[p] = s[p] * inv;
    }
    __syncthreads();
    float w[P_];
    #pragma unroll
    for (int p = 0; p < P_; ++p) w[p] = wsh[p];
    #pragma unroll
    for (int r = 0; r < 4; ++r) {
        float a = 0.0f;
        #pragma unroll
        for (int p = 0; p < P_; ++p) a = fmaf(ar[r][p], w[p], a);
        unsigned short th = f2bf(a);
        unsigned short tl = f2bf(a - bf2f(th));
        ha_hi[(size_t)n * 2048 + 1024 + m0 + r] = th;
        ha_lo[(size_t)n * 2048 + 1024 + m0 + r] = tl;
    }
}

extern "C" void kernel_launch(void* const* d_in, const int* in_sizes, int n_in,
                              void* d_out, int out_size, void* d_ws, size_t ws_size,
                              hipStream_t stream) {
    const float* x     = (const float*)d_in[0];
    const float* A     = (const float*)d_in[1];
    const float* Wx    = (const float*)d_in[2];
    const float* Wh    = (const float*)d_in[3];
    const float* Wattn = (const float*)d_in[4];
    const float* b     = (const float*)d_in[5];
    float* out = (float*)d_out;

    // workspace layout (~158 MB)
    unsigned short* WT_hi = (unsigned short*)d_ws;                 // 4096*3072
    unsigned short* WT_lo = WT_hi + (size_t)G_ * KTOT;             // 4096*3072
    unsigned short* Xhi   = WT_lo + (size_t)G_ * KTOT;             // 256*64*1024
    unsigned short* Xlo   = Xhi + (size_t)N_ * T_ * D_;            // 256*64*1024
    unsigned short* ha_hi = Xlo + (size_t)N_ * T_ * D_;            // 256*2048
    unsigned short* ha_lo = ha_hi + (size_t)N_ * 2048;             // 256*2048
    float* c_buf = (float*)(ha_lo + (size_t)N_ * 2048);            // 256*1024
    float* parts = c_buf + (size_t)N_ * H_;                        // 8*256*4096

    prep_weights<<<dim3(64, 16, 3), 256, 0, stream>>>(Wx, Wh, Wattn, WT_hi, WT_lo);
    prep_x<<<dim3(N_, T_), 256, 0, stream>>>(x, Xhi, Xlo);
    init_kernel<<<N_, 256, 0, stream>>>(A, c_buf, ha_hi, ha_lo);

    for (int t = 0; t < T_; ++t) {
        gemm_kernel<<<dim3(32, 2, KSPLIT), 256, 0, stream>>>(
            Xhi, Xlo, t, ha_hi, ha_lo, WT_hi, WT_lo, parts);
        gates_kernel<<<N_, 256, 0, stream>>>(parts, b, A, c_buf, ha_hi, ha_lo, out, t);
    }
}

// Round 4
// 2432.304 us; speedup vs baseline: 5.4665x; 1.0403x over previous
//
#include <hip/hip_runtime.h>

#define N_ 256
#define T_ 64
#define D_ 1024
#define H_ 1024
#define G_ 4096   // 4*H
#define P_ 16     // 4x4 spatial positions
#define KTOT 3072 // D + H + H
#define INV_SQRT_H 0.03125f
#define KSPLIT 8
#define KPB 384   // K per split-K block (12 k-steps of 32)

typedef __attribute__((ext_vector_type(8))) short short8_t;
typedef __attribute__((ext_vector_type(4))) float f32x4;

__device__ __forceinline__ unsigned short f2bf(float f) {
    unsigned int u = __float_as_uint(f);
    unsigned int r = (u + 0x7FFFu + ((u >> 16) & 1u)) >> 16;  // RNE
    return (unsigned short)r;
}
__device__ __forceinline__ float bf2f(unsigned short h) {
    return __uint_as_float(((unsigned int)h) << 16);
}
__device__ __forceinline__ float fsig(float x) { return 1.0f / (1.0f + __expf(-x)); }
__device__ __forceinline__ float ftanh(float x) { return 1.0f - 2.0f / (__expf(2.0f * x) + 1.0f); }

// async global->LDS, 16 bytes per lane; LDS dest = uniform base + lane*16
__device__ __forceinline__ void gl_lds16(const void* g, void* l) {
    __builtin_amdgcn_global_load_lds(
        (const __attribute__((address_space(1))) unsigned int*)g,
        (__attribute__((address_space(3))) unsigned int*)l, 16, 0, 0);
}

// ---------------------------------------------------------------------------
// Transpose + hi/lo-split weights into WT_hi/WT_lo: (4096 j) x (3072 k) bf16,
// k-concat [Wx | Wh | Wattn]. grid (64, 16, 3), block 256.
// ---------------------------------------------------------------------------
__global__ __launch_bounds__(256) void prep_weights(
    const float* __restrict__ Wx, const float* __restrict__ Wh,
    const float* __restrict__ Wattn,
    unsigned short* __restrict__ WT_hi, unsigned short* __restrict__ WT_lo)
{
    __shared__ float tr[64][65];
    const int tid = threadIdx.x;
    const int j0 = blockIdx.x * 64;
    const int k0 = blockIdx.y * 64;
    const int mat = blockIdx.z;
    const float* src = (mat == 0) ? Wx : (mat == 1) ? Wh : Wattn;
    const int koff = mat * 1024;

    #pragma unroll
    for (int l = 0; l < 4; ++l) {
        const int flat = l * 256 + tid;
        const int kk = flat >> 4;
        const int jj4 = (flat & 15) * 4;
        float4 v = *(const float4*)(src + (size_t)(k0 + kk) * G_ + j0 + jj4);
        tr[kk][jj4] = v.x; tr[kk][jj4 + 1] = v.y; tr[kk][jj4 + 2] = v.z; tr[kk][jj4 + 3] = v.w;
    }
    __syncthreads();
    #pragma unroll
    for (int l = 0; l < 8; ++l) {
        const int flat = l * 256 + tid;
        const int jj = flat >> 5;
        const int kk = (flat & 31) * 2;
        float v0 = tr[kk][jj], v1 = tr[kk + 1][jj];
        size_t o = (size_t)(j0 + jj) * KTOT + koff + k0 + kk;
        ushort2 h, lo;
        h.x = f2bf(v0); h.y = f2bf(v1);
        lo.x = f2bf(v0 - bf2f(h.x)); lo.y = f2bf(v1 - bf2f(h.y));
        *(ushort2*)&WT_hi[o] = h;
        *(ushort2*)&WT_lo[o] = lo;
    }
}

// ---------------------------------------------------------------------------
// Split x into bf16 hi/lo. 16 floats per thread. grid 4096, block 256.
// ---------------------------------------------------------------------------
__global__ __launch_bounds__(256) void prep_x(
    const float* __restrict__ x,
    unsigned short* __restrict__ Xhi, unsigned short* __restrict__ Xlo)
{
    const size_t base = ((size_t)blockIdx.x * 256 + threadIdx.x) * 16;
    #pragma unroll
    for (int i = 0; i < 4; ++i) {
        const size_t o = base + i * 4;
        float4 v = *(const float4*)(x + o);
        ushort4 hi, lo;
        hi.x = f2bf(v.x); lo.x = f2bf(v.x - bf2f(hi.x));
        hi.y = f2bf(v.y); lo.y = f2bf(v.y - bf2f(hi.y));
        hi.z = f2bf(v.z); lo.z = f2bf(v.z - bf2f(hi.z));
        hi.w = f2bf(v.w); lo.w = f2bf(v.w - bf2f(hi.w));
        *(ushort4*)&Xhi[o] = hi;
        *(ushort4*)&Xlo[o] = lo;
    }
}

// ---------------------------------------------------------------------------
// init: h0=c0=mean_p A; scores0 -> softmax -> attn0; write ha=[h0|attn0] hi/lo.
// grid N_, block 256; thread handles 4 consecutive h (m0=tid*4).
// ---------------------------------------------------------------------------
__global__ __launch_bounds__(256) void init_kernel(
    const float* __restrict__ A,
    float* __restrict__ c_buf,
    unsigned short* __restrict__ ha_hi, unsigned short* __restrict__ ha_lo)
{
    const int n = blockIdx.x, tid = threadIdx.x;
    const int m0 = tid * 4;
    const float* An = A + (size_t)n * H_ * P_;
    __shared__ float sred[4][P_];
    __shared__ float wsh[P_];

    float ar[4][P_];
    float hv[4];
    float sc[P_];
    #pragma unroll
    for (int p = 0; p < P_; ++p) sc[p] = 0.0f;

    #pragma unroll
    for (int r = 0; r < 4; ++r) {
        const float4* row = (const float4*)(An + (size_t)(m0 + r) * P_);
        float4 v0 = row[0], v1 = row[1], v2 = row[2], v3 = row[3];
        ar[r][0]=v0.x; ar[r][1]=v0.y; ar[r][2]=v0.z; ar[r][3]=v0.w;
        ar[r][4]=v1.x; ar[r][5]=v1.y; ar[r][6]=v1.z; ar[r][7]=v1.w;
        ar[r][8]=v2.x; ar[r][9]=v2.y; ar[r][10]=v2.z; ar[r][11]=v2.w;
        ar[r][12]=v3.x; ar[r][13]=v3.y; ar[r][14]=v3.z; ar[r][15]=v3.w;
        float s = 0.0f;
        #pragma unroll
        for (int p = 0; p < P_; ++p) s += ar[r][p];
        hv[r] = s * (1.0f / 16.0f);
        #pragma unroll
        for (int p = 0; p < P_; ++p) sc[p] += hv[r] * ar[r][p];
    }
    float4 c4; c4.x = hv[0]; c4.y = hv[1]; c4.z = hv[2]; c4.w = hv[3];
    *(float4*)(c_buf + (size_t)n * H_ + m0) = c4;
    ushort4 hh, hl;
    hh.x=f2bf(hv[0]); hh.y=f2bf(hv[1]); hh.z=f2bf(hv[2]); hh.w=f2bf(hv[3]);
    hl.x=f2bf(hv[0]-bf2f(hh.x)); hl.y=f2bf(hv[1]-bf2f(hh.y));
    hl.z=f2bf(hv[2]-bf2f(hh.z)); hl.w=f2bf(hv[3]-bf2f(hh.w));
    *(ushort4*)&ha_hi[(size_t)n * 2048 + m0] = hh;
    *(ushort4*)&ha_lo[(size_t)n * 2048 + m0] = hl;

    #pragma unroll
    for (int off = 32; off > 0; off >>= 1)
        #pragma unroll
        for (int p = 0; p < P_; ++p) sc[p] += __shfl_down(sc[p], off);
    if ((tid & 63) == 0) {
        #pragma unroll
        for (int p = 0; p < P_; ++p) sred[tid >> 6][p] = sc[p];
    }
    __syncthreads();
    if (tid == 0) {
        float s[P_], m = -1e30f;
        #pragma unroll
        for (int p = 0; p < P_; ++p) {
            s[p] = (sred[0][p] + sred[1][p] + sred[2][p] + sred[3][p]) * INV_SQRT_H;
            m = fmaxf(m, s[p]);
        }
        float sum = 0.0f;
        #pragma unroll
        for (int p = 0; p < P_; ++p) { s[p] = __expf(s[p] - m); sum += s[p]; }
        float inv = 1.0f / sum;
        #pragma unroll
        for (int p = 0; p < P_; ++p) wsh[p] = s[p] * inv;
    }
    __syncthreads();
    float w[P_];
    #pragma unroll
    for (int p = 0; p < P_; ++p) w[p] = wsh[p];
    float at[4];
    #pragma unroll
    for (int r = 0; r < 4; ++r) {
        float a = 0.0f;
        #pragma unroll
        for (int p = 0; p < P_; ++p) a = fmaf(ar[r][p], w[p], a);
        at[r] = a;
    }
    ushort4 th, tl;
    th.x=f2bf(at[0]); th.y=f2bf(at[1]); th.z=f2bf(at[2]); th.w=f2bf(at[3]);
    tl.x=f2bf(at[0]-bf2f(th.x)); tl.y=f2bf(at[1]-bf2f(th.y));
    tl.z=f2bf(at[2]-bf2f(th.z)); tl.w=f2bf(at[3]-bf2f(th.w));
    *(ushort4*)&ha_hi[(size_t)n * 2048 + 1024 + m0] = th;
    *(ushort4*)&ha_lo[(size_t)n * 2048 + 1024 + m0] = tl;
}

// ---------------------------------------------------------------------------
// MFMA GEMM, double-buffered async global_load_lds staging.
// parts[kz][n][j] = sum_{k in kz} Acat[n][k] * W[k][j]
// Acat = [Xsplit(t) | ha], all bf16 hi/lo. BM=BN=128, BK=32, 4 waves (2x2),
// wave tile 64x64, 3-pass hi/lo. grid (32, 2, KSPLIT), block 256.
// LDS rows unpadded 32 shorts; 16B-chunks XOR-swizzled by row&3 (2-way = free).
// One barrier per k-iter: prefetch k+1 issued before compute(k), so the
// compiler's vmcnt(0)-before-s_barrier drain lands after ~500 cyc of MFMA.
// ---------------------------------------------------------------------------
__global__ __launch_bounds__(256) void gemm_kernel(
    const unsigned short* __restrict__ Xhi, const unsigned short* __restrict__ Xlo, int t,
    const unsigned short* __restrict__ ha_hi, const unsigned short* __restrict__ ha_lo,
    const unsigned short* __restrict__ WT_hi, const unsigned short* __restrict__ WT_lo,
    float* __restrict__ parts)
{
    // [buf][tile: 0=Ahi 1=Alo 2=Bhi 3=Blo][row][k]  -> 64 KB
    __shared__ unsigned short buf[2][4][128][32];
    const int tid = threadIdx.x;
    const int j0 = blockIdx.x * 128;
    const int n0 = blockIdx.y * 128;
    const int kz = blockIdx.z;
    const int w = tid >> 6, lane = tid & 63;
    const int wm = w & 1, wn = w >> 1;
    const int quad = lane >> 4, l15 = lane & 15;
    const int lrow = lane >> 2;                 // 0..15 within a 16-row slab
    const int gchunk = (lane & 3) ^ (lrow & 3); // swizzled global 16B chunk

    f32x4 acc[4][4];
    #pragma unroll
    for (int mt = 0; mt < 4; ++mt)
        #pragma unroll
        for (int nt = 0; nt < 4; ++nt) acc[mt][nt] = (f32x4){0.f, 0.f, 0.f, 0.f};

    auto stage = [&](int ks, int bsel) {
        const int kglob = kz * KPB + ks * 32;
        const unsigned short* pAhi;
        const unsigned short* pAlo;
        size_t rstride, coff;
        if (kglob < 1024) {
            pAhi = Xhi + (size_t)t * D_;  pAlo = Xlo + (size_t)t * D_;
            rstride = (size_t)T_ * D_;    coff = kglob;
        } else {
            pAhi = ha_hi;  pAlo = ha_lo;
            rstride = 2048;               coff = kglob - 1024;
        }
        #pragma unroll
        for (int i = 0; i < 2; ++i) {
            const int row = w * 32 + i * 16 + lrow;   // per-lane row in tile
            const int rb = w * 32 + i * 16;           // uniform LDS slab base
            gl_lds16(pAhi + (size_t)(n0 + row) * rstride + coff + gchunk * 8, &buf[bsel][0][rb][0]);
            gl_lds16(pAlo + (size_t)(n0 + row) * rstride + coff + gchunk * 8, &buf[bsel][1][rb][0]);
            gl_lds16(WT_hi + (size_t)(j0 + row) * KTOT + kglob + gchunk * 8, &buf[bsel][2][rb][0]);
            gl_lds16(WT_lo + (size_t)(j0 + row) * KTOT + kglob + gchunk * 8, &buf[bsel][3][rb][0]);
        }
    };

    stage(0, 0);
    __syncthreads();

    for (int ks = 0; ks < KPB / 32; ++ks) {
        const int cur = ks & 1;
        if (ks + 1 < KPB / 32) stage(ks + 1, cur ^ 1);

        short8_t bh[4], bl[4];
        #pragma unroll
        for (int nt = 0; nt < 4; ++nt) {
            const int jr = wn * 64 + nt * 16 + l15;
            const int c = (quad ^ (jr & 3)) * 8;
            bh[nt] = *(const short8_t*)&buf[cur][2][jr][c];
            bl[nt] = *(const short8_t*)&buf[cur][3][jr][c];
        }
        #pragma unroll
        for (int mt = 0; mt < 4; ++mt) {
            const int mr = wm * 64 + mt * 16 + l15;
            const int c = (quad ^ (mr & 3)) * 8;
            short8_t ah = *(const short8_t*)&buf[cur][0][mr][c];
            short8_t al = *(const short8_t*)&buf[cur][1][mr][c];
            #pragma unroll
            for (int nt = 0; nt < 4; ++nt) {
                acc[mt][nt] = __builtin_amdgcn_mfma_f32_16x16x32_bf16(al, bh[nt], acc[mt][nt], 0, 0, 0);
                acc[mt][nt] = __builtin_amdgcn_mfma_f32_16x16x32_bf16(ah, bl[nt], acc[mt][nt], 0, 0, 0);
                acc[mt][nt] = __builtin_amdgcn_mfma_f32_16x16x32_bf16(ah, bh[nt], acc[mt][nt], 0, 0, 0);
            }
        }
        __syncthreads();  // buf[cur] free for ks+2; buf[cur^1] loads drained
    }

    // epilogue: C/D layout col=lane&15, row=quad*4+reg (verified m89/m91)
    #pragma unroll
    for (int mt = 0; mt < 4; ++mt) {
        const int r0 = n0 + wm * 64 + mt * 16 + quad * 4;
        #pragma unroll
        for (int nt = 0; nt < 4; ++nt) {
            const int cc = j0 + wn * 64 + nt * 16 + l15;
            #pragma unroll
            for (int reg = 0; reg < 4; ++reg)
                parts[((size_t)kz * N_ + r0 + reg) * G_ + cc] = acc[mt][nt][reg];
        }
    }
}

// ---------------------------------------------------------------------------
// gates: a = sum_z parts + b; LSTM update; write d_out, ha h-part;
// then scores_{t+1} reduce + softmax + attn_{t+1} (fused).
// grid N_, block 256; thread handles 4 consecutive h.
// ---------------------------------------------------------------------------
__global__ __launch_bounds__(256) void gates_kernel(
    const float* __restrict__ parts, const float* __restrict__ bvec,
    const float* __restrict__ A, float* __restrict__ c_buf,
    unsigned short* __restrict__ ha_hi, unsigned short* __restrict__ ha_lo,
    float* __restrict__ out, int t)
{
    const int n = blockIdx.x, tid = threadIdx.x;
    const int m0 = tid * 4;
    const float* An = A + (size_t)n * H_ * P_;
    __shared__ float sred[4][P_];
    __shared__ float wsh[P_];

    float ar[4][P_];
    #pragma unroll
    for (int r = 0; r < 4; ++r) {
        const float4* row = (const float4*)(An + (size_t)(m0 + r) * P_);
        float4 v0 = row[0], v1 = row[1], v2 = row[2], v3 = row[3];
        ar[r][0]=v0.x; ar[r][1]=v0.y; ar[r][2]=v0.z; ar[r][3]=v0.w;
        ar[r][4]=v1.x; ar[r][5]=v1.y; ar[r][6]=v1.z; ar[r][7]=v1.w;
        ar[r][8]=v2.x; ar[r][9]=v2.y; ar[r][10]=v2.z; ar[r][11]=v2.w;
        ar[r][12]=v3.x; ar[r][13]=v3.y; ar[r][14]=v3.z; ar[r][15]=v3.w;
    }

    float ga[4][4];
    #pragma unroll
    for (int g = 0; g < 4; ++g) {
        const int j = g * 1024 + m0;
        float4 s = *(const float4*)(bvec + j);
        #pragma unroll
        for (int z = 0; z < KSPLIT; ++z) {
            float4 p = *(const float4*)(parts + ((size_t)z * N_ + n) * G_ + j);
            s.x += p.x; s.y += p.y; s.z += p.z; s.w += p.w;
        }
        ga[g][0] = s.x; ga[g][1] = s.y; ga[g][2] = s.z; ga[g][3] = s.w;
    }

    float4 c4 = *(const float4*)(c_buf + (size_t)n * H_ + m0);
    float cold[4] = {c4.x, c4.y, c4.z, c4.w};
    float nh[4], ncv[4];
    #pragma unroll
    for (int r = 0; r < 4; ++r) {
        float nc = fsig(ga[1][r]) * cold[r] + fsig(ga[0][r]) * ftanh(ga[3][r]);
        ncv[r] = nc;
        nh[r] = fsig(ga[2][r]) * ftanh(nc);
    }
    float4 co; co.x = ncv[0]; co.y = ncv[1]; co.z = ncv[2]; co.w = ncv[3];
    *(float4*)(c_buf + (size_t)n * H_ + m0) = co;
    float4 ho; ho.x = nh[0]; ho.y = nh[1]; ho.z = nh[2]; ho.w = nh[3];
    *(float4*)(out + ((size_t)n * T_ + t) * H_ + m0) = ho;
    ushort4 hh, hl;
    hh.x=f2bf(nh[0]); hh.y=f2bf(nh[1]); hh.z=f2bf(nh[2]); hh.w=f2bf(nh[3]);
    hl.x=f2bf(nh[0]-bf2f(hh.x)); hl.y=f2bf(nh[1]-bf2f(hh.y));
    hl.z=f2bf(nh[2]-bf2f(hh.z)); hl.w=f2bf(nh[3]-bf2f(hh.w));
    *(ushort4*)&ha_hi[(size_t)n * 2048 + m0] = hh;
    *(ushort4*)&ha_lo[(size_t)n * 2048 + m0] = hl;

    float sc[P_];
    #pragma unroll
    for (int p = 0; p < P_; ++p) {
        float s = 0.0f;
        #pragma unroll
        for (int r = 0; r < 4; ++r) s = fmaf(nh[r], ar[r][p], s);
        sc[p] = s;
    }
    #pragma unroll
    for (int off = 32; off > 0; off >>= 1)
        #pragma unroll
        for (int p = 0; p < P_; ++p) sc[p] += __shfl_down(sc[p], off);
    if ((tid & 63) == 0) {
        #pragma unroll
        for (int p = 0; p < P_; ++p) sred[tid >> 6][p] = sc[p];
    }
    __syncthreads();
    if (tid == 0) {
        float s[P_], m = -1e30f;
        #pragma unroll
        for (int p = 0; p < P_; ++p) {
            s[p] = (sred[0][p] + sred[1][p] + sred[2][p] + sred[3][p]) * INV_SQRT_H;
            m = fmaxf(m, s[p]);
        }
        float sum = 0.0f;
        #pragma unroll
        for (int p = 0; p < P_; ++p) { s[p] = __expf(s[p] - m); sum += s[p]; }
        float inv = 1.0f / sum;
        #pragma unroll
        for (int p = 0; p < P_; ++p) wsh[p] = s[p] * inv;
    }
    __syncthreads();
    float w[P_];
    #pragma unroll
    for (int p = 0; p < P_; ++p) w[p] = wsh[p];
    #pragma unroll
    for (int r = 0; r < 4; ++r) {
        float a = 0.0f;
        #pragma unroll
        for (int p = 0; p < P_; ++p) a = fmaf(ar[r][p], w[p], a);
        unsigned short th = f2bf(a);
        unsigned short tl = f2bf(a - bf2f(th));
        ha_hi[(size_t)n * 2048 + 1024 + m0 + r] = th;
        ha_lo[(size_t)n * 2048 + 1024 + m0 + r] = tl;
    }
}

extern "C" void kernel_launch(void* const* d_in, const int* in_sizes, int n_in,
                              void* d_out, int out_size, void* d_ws, size_t ws_size,
                              hipStream_t stream) {
    const float* x     = (const float*)d_in[0];
    const float* A     = (const float*)d_in[1];
    const float* Wx    = (const float*)d_in[2];
    const float* Wh    = (const float*)d_in[3];
    const float* Wattn = (const float*)d_in[4];
    const float* b     = (const float*)d_in[5];
    float* out = (float*)d_out;

    // workspace layout (~158 MB)
    unsigned short* WT_hi = (unsigned short*)d_ws;                 // 4096*3072
    unsigned short* WT_lo = WT_hi + (size_t)G_ * KTOT;             // 4096*3072
    unsigned short* Xhi   = WT_lo + (size_t)G_ * KTOT;             // 256*64*1024
    unsigned short* Xlo   = Xhi + (size_t)N_ * T_ * D_;            // 256*64*1024
    unsigned short* ha_hi = Xlo + (size_t)N_ * T_ * D_;            // 256*2048
    unsigned short* ha_lo = ha_hi + (size_t)N_ * 2048;             // 256*2048
    float* c_buf = (float*)(ha_lo + (size_t)N_ * 2048);            // 256*1024
    float* parts = c_buf + (size_t)N_ * H_;                        // 8*256*4096

    prep_weights<<<dim3(64, 16, 3), 256, 0, stream>>>(Wx, Wh, Wattn, WT_hi, WT_lo);
    prep_x<<<4096, 256, 0, stream>>>(x, Xhi, Xlo);
    init_kernel<<<N_, 256, 0, stream>>>(A, c_buf, ha_hi, ha_lo);

    for (int t = 0; t < T_; ++t) {
        gemm_kernel<<<dim3(32, 2, KSPLIT), 256, 0, stream>>>(
            Xhi, Xlo, t, ha_hi, ha_lo, WT_hi, WT_lo, parts);
        gates_kernel<<<N_, 256, 0, stream>>>(parts, b, A, c_buf, ha_hi, ha_lo, out, t);
    }
}